// Round 30
// baseline (375.338 us; speedup 1.0000x reference)
//
#include <hip/hip_runtime.h>
#include <hip/hip_bf16.h>

typedef unsigned long long ull;

// ---------------- problem constants ----------------
constexpr int BATCH = 8;
constexpr int NA    = 261888;
constexpr int KSEL  = 6000;          // PRE_NMS_LIMIT
constexpr int PROP  = 1000;          // PROPOSAL_COUNT
constexpr int CAP   = 8192;          // candidate capacity
constexpr int NBINS = 8192;          // histogram bins
constexpr int HB    = 16;            // private histogram blocks per batch
constexpr int NBLK  = 94;            // 64-col words
constexpr int NBLK0 = 48;            // chunk0 words 0..47
constexpr int SPLIT = 3072;
constexpr int MC0_W = 48;
constexpr int MC1_W = 46;
constexpr int MC0_SZ = SPLIT * MC0_W;            // 147456
constexpr int MC1_SZ = (KSEL - SPLIT) * MC1_W;   // 134688
constexpr int MBATCH = MC0_SZ + MC1_SZ;          // 282144
constexpr int NB128  = 47;           // 128-row decision blocks
constexpr int M0     = 24;           // phase0 blocks 0..23 (words 0..47)

// workspace layout (bytes)
constexpr size_t OFF_CNT   = 0;                       // 512
constexpr size_t OFF_TSEL  = 512;                     // 32
constexpr size_t OFF_KC    = 544;                     // 64
constexpr size_t OFF_BOXES = 608;                     // 768000
constexpr size_t OFF_MASK  = 768608;                  // 18,057,216
constexpr size_t OFF_DIAG  = OFF_MASK + 18057216;     // 8*47*3*64*8 = 577536
constexpr size_t OFF_SUP   = OFF_DIAG + 577536;       // 8*47*4*64*8 = 770048
constexpr size_t OFF_SKG   = OFF_SUP + 770048;        // 32768
constexpr size_t OFF_GS    = OFF_SKG + 32768;         // 6016
constexpr size_t OFF_KEYS  = OFF_MASK;                // aliased (dead pre-mask)
constexpr size_t OFF_HIST  = OFF_MASK + 2097152;      // aliased (dead pre-mask)
// total ~20.2 MB

__device__ __forceinline__ int score_bin(float s) {
  int b = (int)(s * (float)NBINS);
  if (b < 0) b = 0;
  if (b > NBINS - 1) b = NBINS - 1;
  return b;
}

// ---------------- 1. histogram (+ init) ----------------
__global__ __launch_bounds__(256) void hist_kernel(const float4* __restrict__ probs4,
                                                   unsigned int* __restrict__ hist,
                                                   int* __restrict__ cnt,
                                                   ull* __restrict__ keys,
                                                   ull* __restrict__ gS) {
  __shared__ unsigned int lh[NBINS];
  for (int i = threadIdx.x; i < NBINS; i += 256) lh[i] = 0u;
  int fb = blockIdx.y * HB + blockIdx.x;
  if (threadIdx.x == 0) cnt[fb] = 0;
  {
    ull* kp = keys + (size_t)fb * 512;
    for (int i = threadIdx.x; i < 512; i += 256) kp[i] = ~0ull;
  }
  if (fb == 0) {
    for (int i = threadIdx.x; i < BATCH * NBLK; i += 256) gS[i] = 0ull;
  }
  __syncthreads();
  int b = blockIdx.y;
  const float4* p = probs4 + (size_t)b * (NA / 2);
  for (int a = blockIdx.x * 256 + threadIdx.x; a < NA / 2; a += HB * 256) {
    float4 v = p[a];
    atomicAdd(&lh[score_bin(v.y)], 1u);
    atomicAdd(&lh[score_bin(v.w)], 1u);
  }
  __syncthreads();
  unsigned int* gh = hist + ((size_t)b * HB + blockIdx.x) * NBINS;
  for (int i = threadIdx.x; i < NBINS; i += 256) gh[i] = lh[i];
}

// ---------------- 2. threshold bin select ----------------
__global__ __launch_bounds__(256) void thresh_kernel(const unsigned int* __restrict__ hist,
                                                     int* __restrict__ tsel) {
  constexpr int GR = NBINS / 256;
  __shared__ unsigned int ch[NBINS];
  __shared__ unsigned int gsum[256];
  int b = blockIdx.x;
  const unsigned int* h = hist + (size_t)b * HB * NBINS;
  for (int bin = threadIdx.x; bin < NBINS; bin += 256) {
    unsigned int s = 0;
    for (int k = 0; k < HB; ++k) s += h[(size_t)k * NBINS + bin];
    ch[bin] = s;
  }
  __syncthreads();
  unsigned int s = 0;
  int g0 = threadIdx.x * GR;
  for (int i = 0; i < GR; ++i) s += ch[g0 + i];
  gsum[threadIdx.x] = s;
  __syncthreads();
  if (threadIdx.x == 0) {
    unsigned int acc = 0;
    int g = 255;
    for (; g > 0; --g) {
      if (acc + gsum[g] >= (unsigned)KSEL) break;
      acc += gsum[g];
    }
    int t = g * GR;
    for (int bin = g * GR + GR - 1; bin >= g * GR; --bin) {
      acc += ch[bin];
      if (acc >= (unsigned)KSEL) { t = bin; break; }
    }
    tsel[b] = t;
  }
}

// ---------------- 3. compact candidates ----------------
__global__ __launch_bounds__(256) void compact_kernel(const float4* __restrict__ probs4,
                                                      const int* __restrict__ tsel,
                                                      int* __restrict__ cnt,
                                                      ull* __restrict__ keys) {
  __shared__ int lcnt, lbase;
  __shared__ ull lbuf[2048];
  int b = blockIdx.y;
  int t = tsel[b];
  if (threadIdx.x == 0) lcnt = 0;
  __syncthreads();
  const float4* p = probs4 + (size_t)b * (NA / 2);
  for (int a = blockIdx.x * blockDim.x + threadIdx.x; a < NA / 2; a += gridDim.x * blockDim.x) {
    float4 v = p[a];
    if (score_bin(v.y) >= t) {
      int pos = atomicAdd(&lcnt, 1);
      unsigned int ib = ~__float_as_uint(v.y);
      lbuf[pos] = ((ull)ib << 32) | (unsigned int)(2 * a);
    }
    if (score_bin(v.w) >= t) {
      int pos = atomicAdd(&lcnt, 1);
      unsigned int ib = ~__float_as_uint(v.w);
      lbuf[pos] = ((ull)ib << 32) | (unsigned int)(2 * a + 1);
    }
  }
  __syncthreads();
  if (threadIdx.x == 0) lbase = atomicAdd(&cnt[b * 16], lcnt);
  __syncthreads();
  int n = lcnt, base = lbase;
  ull* kb = keys + (size_t)b * CAP;
  for (int i = threadIdx.x; i < n; i += 256) {
    int pos = base + i;
    if (pos < CAP) kb[pos] = lbuf[i];
  }
}

// ---------------- 4. fused rank+scatter ----------------
__global__ __launch_bounds__(256) void rankscatter_kernel(const float4* __restrict__ anchors4,
                                                          const float4* __restrict__ bbox4,
                                                          const int* __restrict__ cnt,
                                                          const ull* __restrict__ keys,
                                                          float4* __restrict__ boxes4) {
#pragma clang fp contract(off)
  __shared__ ull tile[1024];
  int b = blockIdx.y;
  int n = cnt[b * 16];
  if (n > CAP) n = CAP;
  int i = blockIdx.x * 256 + threadIdx.x;
  const ull* kb = keys + (size_t)b * CAP;
  ull my = (i < CAP) ? kb[(i < n) ? i : 0] : ~0ull;
  if (i >= n) my = ~0ull;
  unsigned int r = 0;
  int ntile = (n + 1023) & ~1023;
  for (int j0 = 0; j0 < ntile; j0 += 1024) {
    for (int k = threadIdx.x; k < 1024; k += 256) tile[k] = kb[j0 + k];
    __syncthreads();
#pragma unroll 16
    for (int k = 0; k < 1024; ++k) r += (tile[k] < my) ? 1u : 0u;
    __syncthreads();
  }
  if (i >= n || r >= (unsigned)KSEL) return;
  int a = (int)(unsigned int)(my & 0xffffffffull);
  float4 anc = anchors4[(size_t)b * NA + a];
  float4 d   = bbox4[(size_t)b * NA + a];
  float h = anc.z - anc.x;
  float w = anc.w - anc.y;
  float dy = d.x * 0.1f, dx = d.y * 0.1f, dh = d.z * 0.2f, dw = d.w * 0.2f;
  float cy = (anc.x + (0.5f * h)) + (dy * h);
  float cx = (anc.y + (0.5f * w)) + (dx * w);
  float h2 = h * expf(dh);
  float w2 = w * expf(dw);
  float y1 = cy - 0.5f * h2;
  float x1 = cx - 0.5f * w2;
  float y2 = y1 + h2;
  float x2 = x1 + w2;
  y1 = fminf(fmaxf(y1, 0.f), 1.f);
  x1 = fminf(fmaxf(x1, 0.f), 1.f);
  y2 = fminf(fmaxf(y2, 0.f), 1.f);
  x2 = fminf(fmaxf(x2, 0.f), 1.f);
  boxes4[(size_t)b * KSEL + r] = make_float4(y1, x1, y2, x2);
}

// ---------------- 5. suppression mask + 128-block diag/super side-outputs ----------------
// cx==0 waves cover words w0..w0+3 of 128-row block rb2:
//   wv0: word w0 (cols 0-63)  -> cA0 (upper-tri transpose)
//   wv1: word w0+1 (cols 64-127) -> cB0 (rows 0-63, full), cB1 (rows 64-127, upper-tri)
//   wv2/3: words w0+2, w0+3 row-form -> super planes (0 beyond wordLim)
__global__ __launch_bounds__(256) void mask_kernel(const float4* __restrict__ boxes4,
                                                   ull* __restrict__ maskw,
                                                   ull* __restrict__ diagT,
                                                   ull* __restrict__ superT,
                                                   int rb2Base, int rowBase, int wordBase,
                                                   int wordLim, int stride, int chunkOff) {
#pragma clang fp contract(off)
  int cx = blockIdx.x, b = blockIdx.z;
  int rb2 = rb2Base + blockIdx.y;
  int w0 = 2 * rb2;
  int cb0 = w0 + 4 * cx;
  if (cb0 >= wordLim) return;
  __shared__ float4 colbox[4][64];
  __shared__ float  colca[4][64];
  __shared__ ull wtile[128][5];
  int tid = threadIdx.x, wv = tid >> 6, l = tid & 63;
  int cb = cb0 + wv;
  int rA = rb2 * 128 + l, rB = rA + 64;
  float4 zero = make_float4(0.f, 0.f, 0.f, 0.f);
  float4 boxA = (rA < KSEL) ? boxes4[(size_t)b * KSEL + rA] : zero;
  float4 boxB = (rB < KSEL) ? boxes4[(size_t)b * KSEL + rB] : zero;
  float areaA = (boxA.z - boxA.x) * (boxA.w - boxA.y);
  float areaB = (boxB.z - boxB.x) * (boxB.w - boxB.y);
  int c = cb * 64 + l;
  float4 cload = (cb < wordLim && c < KSEL) ? boxes4[(size_t)b * KSEL + c] : zero;
  colbox[wv][l] = cload;
  colca[wv][l] = (cload.z - cload.x) * (cload.w - cload.y);
  __syncthreads();
  ull bitsA = 0ull, bitsB = 0ull;
  if (cb < wordLim) {
#pragma unroll
    for (int u = 0; u < 64; ++u) {
      float4 cbx = colbox[wv][u];
      float ca = colca[wv][u];
      {
        float ih = fmaxf(fminf(boxA.z, cbx.z) - fmaxf(boxA.x, cbx.x), 0.f);
        float iw = fmaxf(fminf(boxA.w, cbx.w) - fmaxf(boxA.y, cbx.y), 0.f);
        float inter = ih * iw;
        float uni = (areaA + ca) - inter;
        float d = fmaf(-0.7f, uni, inter);
        float tt = 6e-7f * uni;
        bool keep;
        if (__builtin_fabsf(d) <= tt) keep = (inter / uni) > 0.7f;
        else keep = d > 0.f;
        if (keep) bitsA |= (1ull << u);
      }
      {
        float ih = fmaxf(fminf(boxB.z, cbx.z) - fmaxf(boxB.x, cbx.x), 0.f);
        float iw = fmaxf(fminf(boxB.w, cbx.w) - fmaxf(boxB.y, cbx.y), 0.f);
        float inter = ih * iw;
        float uni = (areaB + ca) - inter;
        float d = fmaf(-0.7f, uni, inter);
        float tt = 6e-7f * uni;
        bool keep;
        if (__builtin_fabsf(d) <= tt) keep = (inter / uni) > 0.7f;
        else keep = d > 0.f;
        if (keep) bitsB |= (1ull << u);
      }
    }
  }
  if (cx == 0) {
    size_t dbase = ((size_t)b * NB128 + rb2) * 3 * 64;
    size_t sbase = ((size_t)b * NB128 + rb2) * 4 * 64;
    if (wv == 0) {
      bitsA &= (l == 63) ? 0ull : (~0ull << (l + 1));   // upper-tri rows 0-63 x cols 0-63
      ull colT = 0ull;
#pragma unroll
      for (int k = 0; k < 64; ++k) {
        ull bk = __ballot(((bitsA >> k) & 1ull) != 0ull);
        if (l == k) colT = bk;
      }
      diagT[dbase + 0 * 64 + l] = colT;                 // cA0
    }
    if (wv == 1) {
      ull colT = 0ull;
#pragma unroll
      for (int k = 0; k < 64; ++k) {
        ull bk = __ballot(((bitsA >> k) & 1ull) != 0ull);
        if (l == k) colT = bk;
      }
      diagT[dbase + 1 * 64 + l] = colT;                 // cB0 (full)
      bitsB &= (l == 63) ? 0ull : (~0ull << (l + 1));   // upper-tri rows 64-127 x cols 64-127
      ull colT2 = 0ull;
#pragma unroll
      for (int k = 0; k < 64; ++k) {
        ull bk = __ballot(((bitsB >> k) & 1ull) != 0ull);
        if (l == k) colT2 = bk;
      }
      diagT[dbase + 2 * 64 + l] = colT2;                // cB1
    }
    if (wv == 2) {
      superT[sbase + 0 * 64 + l] = bitsA;               // row l, word w0+2
      superT[sbase + 1 * 64 + l] = bitsB;               // row l+64, word w0+2
    }
    if (wv == 3) {
      superT[sbase + 2 * 64 + l] = bitsA;               // row l, word w0+3
      superT[sbase + 3 * 64 + l] = bitsB;               // row l+64, word w0+3
    }
  }
  wtile[l][wv] = bitsA;
  wtile[l + 64][wv] = bitsB;
  __syncthreads();
  int base_row = rb2 * 128;
#pragma unroll
  for (int pass = 0; pass < 2; ++pass) {
    int idx = pass * 256 + tid;
    int rr = idx >> 2, w = idx & 3;
    int row = base_row + rr;
    int cw = cb0 + w;
    if (row < KSEL && cw < wordLim)
      maskw[(size_t)b * MBATCH + chunkOff + (size_t)(row - rowBase) * stride + (cw - wordBase)]
        = wtile[rr][w];
  }
}

// ---------------- 5b. cross-chunk mask: kept chunk0 rows x words 48..93 -> gS ----------------
__global__ __launch_bounds__(64) void maskx_kernel(const float4* __restrict__ boxes4,
                                                   const int* __restrict__ skeepG,
                                                   const int* __restrict__ kc,
                                                   ull* __restrict__ gS) {
#pragma clang fp contract(off)
  __shared__ float4 colbox[64];
  __shared__ float  colca[64];
  int b = blockIdx.z;
  int kept0 = kc[b * 2];
  int rg = blockIdx.y;
  if (rg * 64 >= kept0) return;
  int l = threadIdx.x;
  int w = NBLK0 + blockIdx.x;
  int c = w * 64 + l;
  float4 zero = make_float4(0.f, 0.f, 0.f, 0.f);
  float4 cld = (c < KSEL) ? boxes4[(size_t)b * KSEL + c] : zero;
  colbox[l] = cld;
  colca[l] = (cld.z - cld.x) * (cld.w - cld.y);
  __syncthreads();
  int idx = rg * 64 + l;
  ull bits = 0ull;
  if (idx < kept0) {
    int r = skeepG[b * 1024 + idx];
    float4 rb = boxes4[(size_t)b * KSEL + r];
    float rA = (rb.z - rb.x) * (rb.w - rb.y);
#pragma unroll
    for (int u = 0; u < 64; ++u) {
      float4 cbx = colbox[u];
      float ca = colca[u];
      float ih = fmaxf(fminf(rb.z, cbx.z) - fmaxf(rb.x, cbx.x), 0.f);
      float iw = fmaxf(fminf(rb.w, cbx.w) - fmaxf(rb.y, cbx.y), 0.f);
      float inter = ih * iw;
      float uni = (rA + ca) - inter;
      float d = fmaf(-0.7f, uni, inter);
      float tt = 6e-7f * uni;
      bool keep;
      if (__builtin_fabsf(d) <= tt) keep = (inter / uni) > 0.7f;
      else keep = d > 0.f;
      if (keep) bits |= (1ull << u);
    }
  }
  unsigned lo = (unsigned)bits, hi = (unsigned)(bits >> 32);
#pragma unroll
  for (int m = 1; m < 64; m <<= 1) {
    lo |= (unsigned)__shfl_xor((int)lo, m, 64);
    hi |= (unsigned)__shfl_xor((int)hi, m, 64);
  }
  if (l == 0) {
    ull v = (ull)lo | ((ull)hi << 32);
    if (v) atomicOr(&gS[b * NBLK + w], v);
  }
}

// ---------------- 6. scan: 128-row decision blocks (47 iterations total) ----------------
// Decision (wave 0): lane holds cA0/cB0/cB1 cols; kept u -> 1-2 ballots.
// Urgent: words 2m+2, 2m+3 via 4 super planes + two butterflies.
// Lazy (192 thr): klist[m-1] x words >= 2m+2 (4 subs/word x 48 words).
template<int PHASE>
__global__ __launch_bounds__(256, 1) void scan_kernel(const float4* __restrict__ boxes4,
                                                      const ull* __restrict__ maskw,
                                                      const ull* __restrict__ diagT,
                                                      const ull* __restrict__ superT,
                                                      int* __restrict__ skeepG,
                                                      int* __restrict__ kc,
                                                      const ull* __restrict__ gS,
                                                      float4* __restrict__ out4) {
  __shared__ ull ldiag[M0 * 3 * 64];   // 36864 B
  __shared__ ull lsup[M0 * 4 * 64];    // 49152 B
  __shared__ ull S[96];
  __shared__ ull S_urgA, S_urgB;
  __shared__ int klist[2][128];
  __shared__ int skeep[1024];
  __shared__ int s_kept, s_done, s_klen[2];
  int b = blockIdx.x;
  int tid = threadIdx.x;
  int lane = tid & 63;
  const ull* mb = maskw + (size_t)b * MBATCH;
  const int mB = PHASE ? M0 : 0;
  const int mE = PHASE ? NB128 : M0;
  const int wE = PHASE ? NBLK : NBLK0;

  {
    const ull* dt = diagT + ((size_t)b * NB128 + mB) * 3 * 64;
    int cntd = (mE - mB) * 3 * 64;
    for (int i = tid; i < cntd; i += 256) ldiag[i] = dt[i];
    const ull* st = superT + ((size_t)b * NB128 + mB) * 4 * 64;
    int cnts = (mE - mB) * 4 * 64;
    for (int i = tid; i < cnts; i += 256) lsup[i] = st[i];
  }
  if (PHASE == 0) {
    if (tid < 96) S[tid] = 0ull;
    if (tid == 0) { s_kept = 0; s_done = 0; s_klen[0] = 0; s_klen[1] = 0; S_urgA = 0ull; S_urgB = 0ull; }
  } else {
    int k0 = kc[b * 2], d0 = kc[b * 2 + 1];
    if (tid < 96) S[tid] = (tid >= NBLK0 && tid < NBLK) ? gS[b * NBLK + tid] : 0ull;
    for (int i = tid; i < k0; i += 256) skeep[i] = skeepG[b * 1024 + i];
    if (tid == 0) { s_kept = k0; s_done = d0; s_klen[0] = 0; s_klen[1] = 0; S_urgA = 0ull; S_urgB = 0ull; }
  }
  __syncthreads();

  for (int m = mB; m < mE; ++m) {
    if (s_done) break;
    if (tid < 64) {
      int lm = m - mB;
      ull Sn0 = S[2 * m] | S_urgA;
      ull Sn1 = S[2 * m + 1] | S_urgB;
      ull cA0 = ldiag[(lm * 3 + 0) * 64 + lane];
      ull cB0 = ldiag[(lm * 3 + 1) * 64 + lane];
      ull cB1 = ldiag[(lm * 3 + 2) * 64 + lane];
      ull sA2 = lsup[(lm * 4 + 0) * 64 + lane];
      ull sB2 = lsup[(lm * 4 + 1) * 64 + lane];
      ull sA3 = lsup[(lm * 4 + 2) * 64 + lane];
      ull sB3 = lsup[(lm * 4 + 3) * 64 + lane];
      int base = m * 128;
      int nval = KSEL - base;
      ull valid0 = (nval >= 64) ? ~0ull : ((nval <= 0) ? 0ull : ((1ull << nval) - 1ull));
      int nv1 = nval - 64;
      ull valid1 = (nv1 >= 64) ? ~0ull : ((nv1 <= 0) ? 0ull : ((1ull << nv1) - 1ull));
      ull A0 = ~Sn0 & valid0;
      ull A1 = ~Sn1 & valid1;
      ull K0 = 0ull, K1 = 0ull;
      int kept = s_kept;
      int done = 0;
      while (A0 | A1) {
        bool lo = (A0 != 0ull);
        int u = lo ? __builtin_ctzll(A0) : __builtin_ctzll(A1);
        ++kept;
        if (lo) K0 |= (1ull << u); else K1 |= (1ull << u);
        if (kept >= PROP) { done = 1; break; }
        if (lo) {
          ull sup0 = __ballot(((cA0 >> u) & 1ull) != 0ull);
          ull sup1 = __ballot(((cB0 >> u) & 1ull) != 0ull);
          A0 &= ~(sup0 | (1ull << u));
          A1 &= ~sup1;
        } else {
          ull sup1 = __ballot(((cB1 >> u) & 1ull) != 0ull);
          A1 &= ~(sup1 | (1ull << u));
        }
      }
      int klen0 = __builtin_popcountll(K0);
      int klen  = klen0 + __builtin_popcountll(K1);
      int kbase = kept - klen;
      if ((K0 >> lane) & 1ull) {
        int rank = __builtin_popcountll(K0 & ((1ull << lane) - 1ull));
        skeep[kbase + rank] = base + lane;
        klist[m & 1][rank] = base + lane;
      }
      if ((K1 >> lane) & 1ull) {
        int rank = klen0 + __builtin_popcountll(K1 & ((1ull << lane) - 1ull));
        skeep[kbase + rank] = base + 64 + lane;
        klist[m & 1][rank] = base + 64 + lane;
      }
      int klp = (klen + 3) & ~3;
      int padn = klp - klen;
      if (klen > 0 && lane < padn) {
        int fk = base + ((K0 != 0ull) ? __builtin_ctzll(K0) : (64 + __builtin_ctzll(K1)));
        klist[m & 1][klen + lane] = fk;
      }
      // urgent: words 2m+2 (ua2) and 2m+3 (ua3)
      ull ua2 = 0ull, ua3 = 0ull;
      if ((K0 >> lane) & 1ull) { ua2 |= sA2; ua3 |= sA3; }
      if ((K1 >> lane) & 1ull) { ua2 |= sB2; ua3 |= sB3; }
      unsigned a2lo = (unsigned)ua2, a2hi = (unsigned)(ua2 >> 32);
      unsigned a3lo = (unsigned)ua3, a3hi = (unsigned)(ua3 >> 32);
#pragma unroll
      for (int mm = 1; mm < 64; mm <<= 1) {
        a2lo |= (unsigned)__shfl_xor((int)a2lo, mm, 64);
        a2hi |= (unsigned)__shfl_xor((int)a2hi, mm, 64);
        a3lo |= (unsigned)__shfl_xor((int)a3lo, mm, 64);
        a3hi |= (unsigned)__shfl_xor((int)a3hi, mm, 64);
      }
      if (lane == 0) {
        s_klen[m & 1] = klen;
        S_urgA = (ull)a2lo | ((ull)a2hi << 32);
        S_urgB = (ull)a3lo | ((ull)a3hi << 32);
        s_kept = kept;
        if (done) s_done = 1;
      }
    } else {
      // lazy: klist[m-1] over words >= 2m+2 (within phase word range)
      int prev = (m & 1) ^ 1;
      int kl = s_klen[prev];
      int lt = tid - 64;               // 0..191
      int wi = lt >> 2;                // 0..47
      int sub = lt & 3;
      int w = 2 * m + 2 + wi;
      if (kl > 0 && w < wE) {
        const int* kp = klist[prev];
        int klp4 = (kl + 3) & ~3;
        int per = klp4 >> 2;
        int bs = sub * per;
        ull acc = 0ull;
#pragma unroll 8
        for (int ri = 0; ri < per; ++ri) {
          int r = kp[bs + ri];
          size_t addr = (PHASE == 0) ? ((size_t)r * MC0_W + w)
                                     : ((size_t)MC0_SZ + (size_t)(r - SPLIT) * MC1_W + (w - NBLK0));
          acc |= mb[addr];
        }
        if (acc) atomicOr(&S[w], acc);
      }
    }
    __syncthreads();
  }

  if (PHASE == 0) {
    int k0 = s_kept;
    if (k0 > PROP) k0 = PROP;
    for (int i = tid; i < k0; i += 256) skeepG[b * 1024 + i] = skeep[i];
    if (tid == 0) { kc[b * 2] = k0; kc[b * 2 + 1] = s_done; }
  } else {
    int fin = s_kept;
    if (fin > PROP) fin = PROP;
    const float4* bx = boxes4 + (size_t)b * KSEL;
    for (int r2 = tid; r2 < PROP; r2 += 256) {
      float4 v = make_float4(0.f, 0.f, 0.f, 0.f);
      if (r2 < fin) v = bx[skeep[r2]];
      out4[(size_t)b * PROP + r2] = v;
    }
  }
}

// ---------------- launch (9 dispatches) ----------------
extern "C" void kernel_launch(void* const* d_in, const int* in_sizes, int n_in,
                              void* d_out, int out_size, void* d_ws, size_t ws_size,
                              hipStream_t stream) {
  const float4* probs4  = (const float4*)d_in[0];
  const float4* bbox4   = (const float4*)d_in[1];
  const float4* anchors4= (const float4*)d_in[2];
  float4* out4 = (float4*)d_out;
  char* ws = (char*)d_ws;

  int* cnt           = (int*)(ws + OFF_CNT);
  int* tsel          = (int*)(ws + OFF_TSEL);
  int* kc            = (int*)(ws + OFF_KC);
  float4* boxes4     = (float4*)(ws + OFF_BOXES);
  ull* maskw         = (ull*)(ws + OFF_MASK);
  ull* diagT         = (ull*)(ws + OFF_DIAG);
  ull* superT        = (ull*)(ws + OFF_SUP);
  int* skeepG        = (int*)(ws + OFF_SKG);
  ull* gS            = (ull*)(ws + OFF_GS);
  ull* keys          = (ull*)(ws + OFF_KEYS);
  unsigned int* hist = (unsigned int*)(ws + OFF_HIST);

  hipLaunchKernelGGL(hist_kernel,        dim3(HB, BATCH),    dim3(256), 0, stream, probs4, hist, cnt, keys, gS);
  hipLaunchKernelGGL(thresh_kernel,      dim3(BATCH),        dim3(256), 0, stream, hist, tsel);
  hipLaunchKernelGGL(compact_kernel,     dim3(128, BATCH),   dim3(256), 0, stream, probs4, tsel, cnt, keys);
  hipLaunchKernelGGL(rankscatter_kernel, dim3(32, BATCH),    dim3(256), 0, stream, anchors4, bbox4, cnt, keys, boxes4);
  // chunk0 mask: rows 0..3071, words 0..47 (128-row blocks 0..23)
  hipLaunchKernelGGL(mask_kernel, dim3(12, 24, BATCH), dim3(256), 0, stream,
                     boxes4, maskw, diagT, superT, 0, 0, 0, NBLK0, MC0_W, 0);
  // chunk1 mask: rows 3072..5999, words 48..93 (blocks 24..46)
  hipLaunchKernelGGL(mask_kernel, dim3(12, 23, BATCH), dim3(256), 0, stream,
                     boxes4, maskw, diagT, superT, 24, SPLIT, NBLK0, NBLK, MC1_W, MC0_SZ);
  scan_kernel<0><<<dim3(BATCH), dim3(256), 0, stream>>>(boxes4, maskw, diagT, superT,
                                                        skeepG, kc, gS, out4);
  hipLaunchKernelGGL(maskx_kernel, dim3(NBLK - NBLK0, 16, BATCH), dim3(64), 0, stream,
                     boxes4, skeepG, kc, gS);
  scan_kernel<1><<<dim3(BATCH), dim3(256), 0, stream>>>(boxes4, maskw, diagT, superT,
                                                        skeepG, kc, gS, out4);
}

// Round 31
// 282.496 us; speedup vs baseline: 1.3286x; 1.3286x over previous
//
#include <hip/hip_runtime.h>
#include <hip/hip_bf16.h>

typedef unsigned long long ull;

// ---------------- problem constants ----------------
constexpr int BATCH = 8;
constexpr int NA    = 261888;
constexpr int KSEL  = 6000;          // PRE_NMS_LIMIT
constexpr int PROP  = 1000;          // PROPOSAL_COUNT
constexpr int CAP   = 8192;          // candidate capacity
constexpr int NBINS = 8192;          // histogram bins
constexpr int HB    = 16;            // private histogram blocks per batch
constexpr int NBLK  = 94;            // 64-col words
constexpr int NBLK0 = 48;            // chunk0 words 0..47
constexpr int SPLIT = 3072;
constexpr int MC0_W = 48;
constexpr int MC1_W = 46;
constexpr int MC0_SZ = SPLIT * MC0_W;            // 147456
constexpr int MC1_SZ = (KSEL - SPLIT) * MC1_W;   // 134688
constexpr int MBATCH = MC0_SZ + MC1_SZ;          // 282144

// workspace layout (bytes). keys/hist alias the mask head (disjoint liveness).
constexpr size_t OFF_CNT   = 0;                       // 512 (128 ints)
constexpr size_t OFF_TSEL  = 512;                     // 32
constexpr size_t OFF_KC    = 544;                     // 64 (8 x {kept,done})
constexpr size_t OFF_BOXES = 608;                     // 8*6000*16 = 768000
constexpr size_t OFF_MASK  = 768608;                  // 8*282144*8 = 18,057,216
constexpr size_t OFF_DIAG  = OFF_MASK + 18057216;     // 385024
constexpr size_t OFF_SUP   = OFF_DIAG + 385024;       // 385024
constexpr size_t OFF_SKG   = OFF_SUP + 385024;        // 32768
constexpr size_t OFF_GS    = OFF_SKG + 32768;         // 6016
constexpr size_t OFF_KEYS  = OFF_MASK;                // aliased (dead pre-mask)
constexpr size_t OFF_HIST  = OFF_MASK + 2097152;      // aliased (dead pre-mask)
// total ~19.6 MB

__device__ __forceinline__ int score_bin(float s) {
  int b = (int)(s * (float)NBINS);
  if (b < 0) b = 0;
  if (b > NBINS - 1) b = NBINS - 1;
  return b;
}

// ---------------- 1. histogram (+ init: cnt, keys pad, gS zero) ----------------
__global__ __launch_bounds__(256) void hist_kernel(const float4* __restrict__ probs4,
                                                   unsigned int* __restrict__ hist,
                                                   int* __restrict__ cnt,
                                                   ull* __restrict__ keys,
                                                   ull* __restrict__ gS) {
  __shared__ unsigned int lh[NBINS];
  for (int i = threadIdx.x; i < NBINS; i += 256) lh[i] = 0u;
  int fb = blockIdx.y * HB + blockIdx.x;
  if (threadIdx.x == 0) cnt[fb] = 0;
  {
    ull* kp = keys + (size_t)fb * 512;
    for (int i = threadIdx.x; i < 512; i += 256) kp[i] = ~0ull;
  }
  if (fb == 0) {
    for (int i = threadIdx.x; i < BATCH * NBLK; i += 256) gS[i] = 0ull;
  }
  __syncthreads();
  int b = blockIdx.y;
  const float4* p = probs4 + (size_t)b * (NA / 2);
  for (int a = blockIdx.x * 256 + threadIdx.x; a < NA / 2; a += HB * 256) {
    float4 v = p[a];
    atomicAdd(&lh[score_bin(v.y)], 1u);
    atomicAdd(&lh[score_bin(v.w)], 1u);
  }
  __syncthreads();
  unsigned int* gh = hist + ((size_t)b * HB + blockIdx.x) * NBINS;
  for (int i = threadIdx.x; i < NBINS; i += 256) gh[i] = lh[i];
}

// ---------------- 2. threshold bin select ----------------
__global__ __launch_bounds__(256) void thresh_kernel(const unsigned int* __restrict__ hist,
                                                     int* __restrict__ tsel) {
  constexpr int GR = NBINS / 256;
  __shared__ unsigned int ch[NBINS];
  __shared__ unsigned int gsum[256];
  int b = blockIdx.x;
  const unsigned int* h = hist + (size_t)b * HB * NBINS;
  for (int bin = threadIdx.x; bin < NBINS; bin += 256) {
    unsigned int s = 0;
    for (int k = 0; k < HB; ++k) s += h[(size_t)k * NBINS + bin];
    ch[bin] = s;
  }
  __syncthreads();
  unsigned int s = 0;
  int g0 = threadIdx.x * GR;
  for (int i = 0; i < GR; ++i) s += ch[g0 + i];
  gsum[threadIdx.x] = s;
  __syncthreads();
  if (threadIdx.x == 0) {
    unsigned int acc = 0;
    int g = 255;
    for (; g > 0; --g) {
      if (acc + gsum[g] >= (unsigned)KSEL) break;
      acc += gsum[g];
    }
    int t = g * GR;
    for (int bin = g * GR + GR - 1; bin >= g * GR; --bin) {
      acc += ch[bin];
      if (acc >= (unsigned)KSEL) { t = bin; break; }
    }
    tsel[b] = t;
  }
}

// ---------------- 3. compact candidates (float4 loads) ----------------
__global__ __launch_bounds__(256) void compact_kernel(const float4* __restrict__ probs4,
                                                      const int* __restrict__ tsel,
                                                      int* __restrict__ cnt,
                                                      ull* __restrict__ keys) {
  __shared__ int lcnt, lbase;
  __shared__ ull lbuf[2048];
  int b = blockIdx.y;
  int t = tsel[b];
  if (threadIdx.x == 0) lcnt = 0;
  __syncthreads();
  const float4* p = probs4 + (size_t)b * (NA / 2);
  for (int a = blockIdx.x * blockDim.x + threadIdx.x; a < NA / 2; a += gridDim.x * blockDim.x) {
    float4 v = p[a];
    if (score_bin(v.y) >= t) {
      int pos = atomicAdd(&lcnt, 1);
      unsigned int ib = ~__float_as_uint(v.y);
      lbuf[pos] = ((ull)ib << 32) | (unsigned int)(2 * a);
    }
    if (score_bin(v.w) >= t) {
      int pos = atomicAdd(&lcnt, 1);
      unsigned int ib = ~__float_as_uint(v.w);
      lbuf[pos] = ((ull)ib << 32) | (unsigned int)(2 * a + 1);
    }
  }
  __syncthreads();
  if (threadIdx.x == 0) lbase = atomicAdd(&cnt[b * 16], lcnt);
  __syncthreads();
  int n = lcnt, base = lbase;
  ull* kb = keys + (size_t)b * CAP;
  for (int i = threadIdx.x; i < n; i += 256) {
    int pos = base + i;
    if (pos < CAP) kb[pos] = lbuf[i];
  }
}

// ---------------- 4. fused rank+scatter, LDS-tiled key stream ----------------
__global__ __launch_bounds__(256) void rankscatter_kernel(const float4* __restrict__ anchors4,
                                                          const float4* __restrict__ bbox4,
                                                          const int* __restrict__ cnt,
                                                          const ull* __restrict__ keys,
                                                          float4* __restrict__ boxes4) {
#pragma clang fp contract(off)
  __shared__ ull tile[1024];
  int b = blockIdx.y;
  int n = cnt[b * 16];
  if (n > CAP) n = CAP;
  int i = blockIdx.x * 256 + threadIdx.x;
  const ull* kb = keys + (size_t)b * CAP;
  ull my = (i < CAP) ? kb[(i < n) ? i : 0] : ~0ull;
  if (i >= n) my = ~0ull;
  unsigned int r = 0;
  int ntile = (n + 1023) & ~1023;
  for (int j0 = 0; j0 < ntile; j0 += 1024) {
    for (int k = threadIdx.x; k < 1024; k += 256) tile[k] = kb[j0 + k];
    __syncthreads();
#pragma unroll 16
    for (int k = 0; k < 1024; ++k) r += (tile[k] < my) ? 1u : 0u;
    __syncthreads();
  }
  if (i >= n || r >= (unsigned)KSEL) return;
  int a = (int)(unsigned int)(my & 0xffffffffull);
  float4 anc = anchors4[(size_t)b * NA + a];
  float4 d   = bbox4[(size_t)b * NA + a];
  float h = anc.z - anc.x;
  float w = anc.w - anc.y;
  float dy = d.x * 0.1f, dx = d.y * 0.1f, dh = d.z * 0.2f, dw = d.w * 0.2f;
  float cy = (anc.x + (0.5f * h)) + (dy * h);
  float cx = (anc.y + (0.5f * w)) + (dx * w);
  float h2 = h * expf(dh);
  float w2 = w * expf(dw);
  float y1 = cy - 0.5f * h2;
  float x1 = cx - 0.5f * w2;
  float y2 = y1 + h2;
  float x2 = x1 + w2;
  y1 = fminf(fmaxf(y1, 0.f), 1.f);
  x1 = fminf(fmaxf(x1, 0.f), 1.f);
  y2 = fminf(fmaxf(y2, 0.f), 1.f);
  x2 = fminf(fmaxf(x2, 0.f), 1.f);
  boxes4[(size_t)b * KSEL + r] = make_float4(y1, x1, y2, x2);
}

// ---------------- shared mask body (proven 2-row structure) ----------------
__device__ __forceinline__ void mask_body(const float4* __restrict__ boxes4,
                                          ull* __restrict__ maskw,
                                          ull* __restrict__ diagT,
                                          ull* __restrict__ superT,
                                          int cx, int rb2, int b,
                                          int rowBase, int wordBase,
                                          int wordLim, int stride, int chunkOff) {
#pragma clang fp contract(off)
  __shared__ float4 colbox[4][64];
  __shared__ float  colca[4][64];
  __shared__ ull wtile[128][5];
  int w0 = 2 * rb2;
  int cb0 = w0 + 4 * cx;
  if (cb0 >= wordLim) return;
  int tid = threadIdx.x, wv = tid >> 6, l = tid & 63;
  int cb = cb0 + wv;
  int rA = rb2 * 128 + l, rB = rA + 64;
  float4 zero = make_float4(0.f, 0.f, 0.f, 0.f);
  float4 boxA = (rA < KSEL) ? boxes4[(size_t)b * KSEL + rA] : zero;
  float4 boxB = (rB < KSEL) ? boxes4[(size_t)b * KSEL + rB] : zero;
  float areaA = (boxA.z - boxA.x) * (boxA.w - boxA.y);
  float areaB = (boxB.z - boxB.x) * (boxB.w - boxB.y);
  int c = cb * 64 + l;
  float4 cload = (cb < wordLim && c < KSEL) ? boxes4[(size_t)b * KSEL + c] : zero;
  colbox[wv][l] = cload;
  colca[wv][l] = (cload.z - cload.x) * (cload.w - cload.y);
  __syncthreads();
  ull bitsA = 0ull, bitsB = 0ull;
  if (cb < wordLim) {
#pragma unroll
    for (int u = 0; u < 64; ++u) {
      float4 cbx = colbox[wv][u];
      float ca = colca[wv][u];
      {
        float ih = fmaxf(fminf(boxA.z, cbx.z) - fmaxf(boxA.x, cbx.x), 0.f);
        float iw = fmaxf(fminf(boxA.w, cbx.w) - fmaxf(boxA.y, cbx.y), 0.f);
        float inter = ih * iw;
        float uni = (areaA + ca) - inter;
        float d = fmaf(-0.7f, uni, inter);
        float tt = 6e-7f * uni;
        bool keep;
        if (__builtin_fabsf(d) <= tt) keep = (inter / uni) > 0.7f;
        else keep = d > 0.f;
        if (keep) bitsA |= (1ull << u);
      }
      {
        float ih = fmaxf(fminf(boxB.z, cbx.z) - fmaxf(boxB.x, cbx.x), 0.f);
        float iw = fmaxf(fminf(boxB.w, cbx.w) - fmaxf(boxB.y, cbx.y), 0.f);
        float inter = ih * iw;
        float uni = (areaB + ca) - inter;
        float d = fmaf(-0.7f, uni, inter);
        float tt = 6e-7f * uni;
        bool keep;
        if (__builtin_fabsf(d) <= tt) keep = (inter / uni) > 0.7f;
        else keep = d > 0.f;
        if (keep) bitsB |= (1ull << u);
      }
    }
    if (cb == w0) {
      bitsA &= (l == 63) ? 0ull : (~0ull << (l + 1)); // only cc > row suppress
      ull colT = 0ull;
#pragma unroll
      for (int k = 0; k < 64; ++k) {
        ull bk = __ballot(((bitsA >> k) & 1ull) != 0ull);
        if (l == k) colT = bk;
      }
      diagT[((size_t)b * NBLK + w0) * 64 + l] = colT;
    }
    if (cb == w0 + 1) {
      superT[((size_t)b * NBLK + w0) * 64 + l] = bitsA;  // word w0+1 of block-w0 rows
      bitsB &= (l == 63) ? 0ull : (~0ull << (l + 1));
      ull colT = 0ull;
#pragma unroll
      for (int k = 0; k < 64; ++k) {
        ull bk = __ballot(((bitsB >> k) & 1ull) != 0ull);
        if (l == k) colT = bk;
      }
      diagT[((size_t)b * NBLK + w0 + 1) * 64 + l] = colT;
    }
    if (cb == w0 + 2) {
      superT[((size_t)b * NBLK + w0 + 1) * 64 + l] = bitsB;
    }
  }
  wtile[l][wv] = bitsA;
  wtile[l + 64][wv] = bitsB;
  __syncthreads();
  int base_row = rb2 * 128;
#pragma unroll
  for (int pass = 0; pass < 2; ++pass) {
    int idx = pass * 256 + tid;
    int rr = idx >> 2, w = idx & 3;
    int row = base_row + rr;
    int cw = cb0 + w;
    if (row < KSEL && cw < wordLim)
      maskw[(size_t)b * MBATCH + chunkOff + (size_t)(row - rowBase) * stride + (cw - wordBase)]
        = wtile[rr][w];
  }
}

// ---------------- shared scan body (proven 64-row, 256-thr structure) ----------------
template<int PHASE>
__device__ __forceinline__ void scan_body(const float4* __restrict__ boxes4,
                                          const ull* __restrict__ maskw,
                                          const ull* __restrict__ diagT,
                                          const ull* __restrict__ superT,
                                          int* __restrict__ skeepG,
                                          int* __restrict__ kc,
                                          const ull* __restrict__ gS,
                                          float4* __restrict__ out4,
                                          int b) {
  __shared__ ull ldiagT[NBLK0 * 64];
  __shared__ ull lsuper[NBLK0 * 64];
  __shared__ ull S[96];
  __shared__ ull S_urg;
  __shared__ int klist[2][64];
  __shared__ int skeep[1024];
  __shared__ int s_kept, s_done, s_klen[2];
  int tid = threadIdx.x;
  int lane = tid & 63;
  const ull* mb = maskw + (size_t)b * MBATCH;
  const int nB = PHASE ? NBLK0 : 0;
  const int nE = PHASE ? NBLK : NBLK0;

  const ull* dt = diagT + (size_t)b * NBLK * 64;
  const ull* st = superT + (size_t)b * NBLK * 64;
  for (int i = nB * 64 + tid; i < nE * 64; i += 256) {
    ldiagT[i - nB * 64] = dt[i];
    lsuper[i - nB * 64] = st[i];
  }
  if (PHASE == 0) {
    if (tid < 96) S[tid] = 0ull;
    if (tid == 0) { s_kept = 0; s_done = 0; s_klen[0] = 0; s_klen[1] = 0; S_urg = 0ull; }
  } else {
    int k0 = kc[b * 2], d0 = kc[b * 2 + 1];
    if (tid < 96) S[tid] = (tid >= NBLK0 && tid < NBLK) ? gS[b * NBLK + tid] : 0ull;
    for (int i = tid; i < k0; i += 256) skeep[i] = skeepG[b * 1024 + i];
    if (tid == 0) { s_kept = k0; s_done = d0; s_klen[0] = 0; s_klen[1] = 0; S_urg = 0ull; }
  }
  __syncthreads();

  for (int n = nB; n < nE; ++n) {
    if (s_done) break;
    if (tid < 64) {
      ull Sn = S[n] | S_urg;
      int i0 = n * 64;
      ull colT = ldiagT[i0 - nB * 64 + lane];
      ull sd = (n + 1 < NBLK) ? lsuper[i0 - nB * 64 + lane] : 0ull;
      int nval = KSEL - i0;
      ull valid = (nval >= 64) ? ~0ull : ((1ull << nval) - 1ull);
      ull A = ~Sn & valid;
      ull K = 0ull;
      int kept = s_kept;
      int done = 0;
      while (A) {
        int u = __builtin_ctzll(A);
        ++kept;
        K |= (1ull << u);
        if (kept >= PROP) { done = 1; break; }
        ull sup = __ballot(((colT >> u) & 1ull) != 0ull);
        A &= ~(sup | (1ull << u));
      }
      int klen = __builtin_popcountll(K);
      int kbase = kept - klen;
      if ((K >> lane) & 1ull) {
        int rank = __builtin_popcountll(K & ((1ull << lane) - 1ull));
        skeep[kbase + rank] = i0 + lane;
        klist[n & 1][rank] = i0 + lane;
      }
      int klp = (klen + 3) & ~3;
      if (klen > 0 && lane >= klen && lane < klp)
        klist[n & 1][lane] = i0 + __builtin_ctzll(K);
      unsigned ulo = (unsigned)sd, uhi = (unsigned)(sd >> 32);
      if (!((K >> lane) & 1ull)) { ulo = 0u; uhi = 0u; }
#pragma unroll
      for (int m = 1; m < 64; m <<= 1) {
        ulo |= (unsigned)__shfl_xor((int)ulo, m, 64);
        uhi |= (unsigned)__shfl_xor((int)uhi, m, 64);
      }
      if (lane == 0) {
        s_klen[n & 1] = klen;
        S_urg = (ull)ulo | ((ull)uhi << 32);
        s_kept = kept;
        if (done) s_done = 1;
      }
    } else {
      int prev = (n & 1) ^ 1;
      int kl = s_klen[prev];
      int lt = tid - 64;
      int wi = lt >> 2;
      int sub = lt & 3;
      int w = n + 1 + wi;
      if (kl > 0 && w < nE) {
        const int* kp = klist[prev];
        int klp4 = (kl + 3) & ~3;
        int per = klp4 >> 2;
        int base = sub * per;
        ull acc = 0ull;
#pragma unroll 8
        for (int ri = 0; ri < per; ++ri) {
          int r = kp[base + ri];
          size_t addr = (PHASE == 0) ? ((size_t)r * MC0_W + w)
                                     : ((size_t)MC0_SZ + (size_t)(r - SPLIT) * MC1_W + (w - NBLK0));
          acc |= mb[addr];
        }
        if (acc) atomicOr(&S[w], acc);
      }
    }
    __syncthreads();
  }

  if (PHASE == 0) {
    int k0 = s_kept;
    if (k0 > PROP) k0 = PROP;
    for (int i = tid; i < k0; i += 256) skeepG[b * 1024 + i] = skeep[i];
    if (tid == 0) { kc[b * 2] = k0; kc[b * 2 + 1] = s_done; }
  } else {
    int fin = s_kept;
    if (fin > PROP) fin = PROP;
    const float4* bx = boxes4 + (size_t)b * KSEL;
    for (int r2 = tid; r2 < PROP; r2 += 256) {
      float4 v = make_float4(0.f, 0.f, 0.f, 0.f);
      if (r2 < fin) v = bx[skeep[r2]];
      out4[(size_t)b * PROP + r2] = v;
    }
  }
}

// ---------------- 5. chunk0 mask (standalone: scan<0> depends on it) ----------------
__global__ __launch_bounds__(256) void mask0_kernel(const float4* __restrict__ boxes4,
                                                    ull* __restrict__ maskw,
                                                    ull* __restrict__ diagT,
                                                    ull* __restrict__ superT) {
  mask_body(boxes4, maskw, diagT, superT,
            blockIdx.x, blockIdx.y, blockIdx.z, 0, 0, NBLK0, MC0_W, 0);
}

// ---------------- 6. FUSED: scan<0> (blocks 0..7) + chunk1 mask (blocks 8..2215) ----------------
// mask_c1 is only consumed by scan<1>, so it hides entirely under scan<0>'s ~98us.
__global__ __launch_bounds__(256, 1) void fused0_kernel(const float4* __restrict__ boxes4,
                                                        ull* __restrict__ maskw,
                                                        ull* __restrict__ diagT,
                                                        ull* __restrict__ superT,
                                                        int* __restrict__ skeepG,
                                                        int* __restrict__ kc,
                                                        const ull* __restrict__ gS,
                                                        float4* __restrict__ out4) {
  if (blockIdx.x < 8) {
    scan_body<0>(boxes4, maskw, diagT, superT, skeepG, kc, gS, out4, blockIdx.x);
  } else {
    int idx = blockIdx.x - 8;
    int cx = idx % 12;
    int tmp = idx / 12;
    int rb2 = 24 + (tmp % 23);
    int b = tmp / 23;
    mask_body(boxes4, maskw, diagT, superT,
              cx, rb2, b, SPLIT, NBLK0, NBLK, MC1_W, MC0_SZ);
  }
}

// ---------------- 5b. cross-chunk mask: kept chunk0 rows x words 48..93 -> gS ----------------
__global__ __launch_bounds__(64) void maskx_kernel(const float4* __restrict__ boxes4,
                                                   const int* __restrict__ skeepG,
                                                   const int* __restrict__ kc,
                                                   ull* __restrict__ gS) {
#pragma clang fp contract(off)
  __shared__ float4 colbox[64];
  __shared__ float  colca[64];
  int b = blockIdx.z;
  int kept0 = kc[b * 2];
  int rg = blockIdx.y;
  if (rg * 64 >= kept0) return;
  int l = threadIdx.x;
  int w = NBLK0 + blockIdx.x;
  int c = w * 64 + l;
  float4 zero = make_float4(0.f, 0.f, 0.f, 0.f);
  float4 cld = (c < KSEL) ? boxes4[(size_t)b * KSEL + c] : zero;
  colbox[l] = cld;
  colca[l] = (cld.z - cld.x) * (cld.w - cld.y);
  __syncthreads();
  int idx = rg * 64 + l;
  ull bits = 0ull;
  if (idx < kept0) {
    int r = skeepG[b * 1024 + idx];
    float4 rb = boxes4[(size_t)b * KSEL + r];
    float rA = (rb.z - rb.x) * (rb.w - rb.y);
#pragma unroll
    for (int u = 0; u < 64; ++u) {
      float4 cbx = colbox[u];
      float ca = colca[u];
      float ih = fmaxf(fminf(rb.z, cbx.z) - fmaxf(rb.x, cbx.x), 0.f);
      float iw = fmaxf(fminf(rb.w, cbx.w) - fmaxf(rb.y, cbx.y), 0.f);
      float inter = ih * iw;
      float uni = (rA + ca) - inter;
      float d = fmaf(-0.7f, uni, inter);
      float tt = 6e-7f * uni;
      bool keep;
      if (__builtin_fabsf(d) <= tt) keep = (inter / uni) > 0.7f;
      else keep = d > 0.f;
      if (keep) bits |= (1ull << u);
    }
  }
  unsigned lo = (unsigned)bits, hi = (unsigned)(bits >> 32);
#pragma unroll
  for (int m = 1; m < 64; m <<= 1) {
    lo |= (unsigned)__shfl_xor((int)lo, m, 64);
    hi |= (unsigned)__shfl_xor((int)hi, m, 64);
  }
  if (l == 0) {
    ull v = (ull)lo | ((ull)hi << 32);
    if (v) atomicOr(&gS[b * NBLK + w], v);
  }
}

// ---------------- 7. scan phase 1 ----------------
__global__ __launch_bounds__(256, 1) void scan1_kernel(const float4* __restrict__ boxes4,
                                                       const ull* __restrict__ maskw,
                                                       const ull* __restrict__ diagT,
                                                       const ull* __restrict__ superT,
                                                       int* __restrict__ skeepG,
                                                       int* __restrict__ kc,
                                                       const ull* __restrict__ gS,
                                                       float4* __restrict__ out4) {
  scan_body<1>(boxes4, maskw, diagT, superT, skeepG, kc, gS, out4, blockIdx.x);
}

// ---------------- launch (8 dispatches) ----------------
extern "C" void kernel_launch(void* const* d_in, const int* in_sizes, int n_in,
                              void* d_out, int out_size, void* d_ws, size_t ws_size,
                              hipStream_t stream) {
  const float4* probs4  = (const float4*)d_in[0];
  const float4* bbox4   = (const float4*)d_in[1];
  const float4* anchors4= (const float4*)d_in[2];
  float4* out4 = (float4*)d_out;
  char* ws = (char*)d_ws;

  int* cnt           = (int*)(ws + OFF_CNT);
  int* tsel          = (int*)(ws + OFF_TSEL);
  int* kc            = (int*)(ws + OFF_KC);
  float4* boxes4     = (float4*)(ws + OFF_BOXES);
  ull* maskw         = (ull*)(ws + OFF_MASK);
  ull* diagT         = (ull*)(ws + OFF_DIAG);
  ull* superT        = (ull*)(ws + OFF_SUP);
  int* skeepG        = (int*)(ws + OFF_SKG);
  ull* gS            = (ull*)(ws + OFF_GS);
  ull* keys          = (ull*)(ws + OFF_KEYS);
  unsigned int* hist = (unsigned int*)(ws + OFF_HIST);

  hipLaunchKernelGGL(hist_kernel,        dim3(HB, BATCH),    dim3(256), 0, stream, probs4, hist, cnt, keys, gS);
  hipLaunchKernelGGL(thresh_kernel,      dim3(BATCH),        dim3(256), 0, stream, hist, tsel);
  hipLaunchKernelGGL(compact_kernel,     dim3(128, BATCH),   dim3(256), 0, stream, probs4, tsel, cnt, keys);
  hipLaunchKernelGGL(rankscatter_kernel, dim3(32, BATCH),    dim3(256), 0, stream, anchors4, bbox4, cnt, keys, boxes4);
  // chunk0 mask (scan<0> dependency)
  hipLaunchKernelGGL(mask0_kernel, dim3(12, 24, BATCH), dim3(256), 0, stream,
                     boxes4, maskw, diagT, superT);
  // FUSED: scan<0> + chunk1 mask (independent; hides under the serial scan)
  hipLaunchKernelGGL(fused0_kernel, dim3(8 + 12 * 23 * BATCH), dim3(256), 0, stream,
                     boxes4, maskw, diagT, superT, skeepG, kc, gS, out4);
  hipLaunchKernelGGL(maskx_kernel, dim3(NBLK - NBLK0, 16, BATCH), dim3(64), 0, stream,
                     boxes4, skeepG, kc, gS);
  hipLaunchKernelGGL(scan1_kernel, dim3(BATCH), dim3(256), 0, stream,
                     boxes4, maskw, diagT, superT, skeepG, kc, gS, out4);
}